// Round 5
// baseline (371.434 us; speedup 1.0000x reference)
//
#include <hip/hip_runtime.h>

#define BINS 5
#define PTS  2
constexpr int Bx = 2, Cc = 256, Hh = 100, Ww = 152;
constexpr int HW = Hh * Ww;          // 15200
constexpr float EPS_DIV = 1e-6f;
constexpr float GN_EPS  = 1e-5f;

typedef __attribute__((ext_vector_type(8))) short bfrag;   // 8 bf16 (4 VGPRs)
typedef __attribute__((ext_vector_type(4))) float f32x4;   // MFMA C/D

__device__ __forceinline__ ushort f2bf(float f) {
    union { float f; unsigned u; } v; v.f = f;
    unsigned r = v.u + 0x7fffu + ((v.u >> 16) & 1u);
    return (ushort)(r >> 16);
}
__device__ __forceinline__ float bf2f(ushort h) {
    union { unsigned u; float f; } v; v.u = ((unsigned)h) << 16;
    return v.f;
}
__device__ __forceinline__ float bflo(unsigned u) {
    return __uint_as_float(u << 16);
}
__device__ __forceinline__ float bfhi(unsigned u) {
    return __uint_as_float(u & 0xffff0000u);
}
__device__ __forceinline__ unsigned pack2(float a, float b) {
    return (unsigned)f2bf(a) | ((unsigned)f2bf(b) << 16);
}

// ---------------------------------------------------------------------------
// K0: convert ef_w, hm1_w, merge_w to bf16 (each 131072 elems) + zero GN parts
// ---------------------------------------------------------------------------
__global__ __launch_bounds__(256)
void k_wconv(const float* __restrict__ efw, const float* __restrict__ w1,
             const float* __restrict__ mw, ushort* __restrict__ wb,
             float* __restrict__ part)
{
    if (blockIdx.x == 0 && threadIdx.x < 128) part[threadIdx.x] = 0.f;
    int gid = blockIdx.x * 256 + threadIdx.x;
    int e = gid * 4;                       // 393216 total elements
    int arr = e >> 17, off = e & 131071;
    const float* src = arr == 0 ? efw : (arr == 1 ? w1 : mw);
    float4 v = *(const float4*)(src + off);
    ushort4 o = { f2bf(v.x), f2bf(v.y), f2bf(v.z), f2bf(v.w) };
    *(ushort4*)(wb + e) = o;
}

// ---------------------------------------------------------------------------
// K1: efp[b][p][pix][c] (bf16) = ef_w @ x + ef_b.  MFMA 16x16x32 bf16.
// Register-prefetch double buffer: tile k+1 loads issue before tile k MFMAs.
// ---------------------------------------------------------------------------
__global__ __launch_bounds__(256)
void k_ef(const float* __restrict__ x, const ushort* __restrict__ wbe,
          const float* __restrict__ efb, ushort* __restrict__ efp)
{
    __shared__ ushort As[128 * 72];     // [n][k] pad 72
    __shared__ ushort Bs[64 * 72];      // [pix][k]
    const int t = threadIdx.x;
    const int wv = t >> 6, ln = t & 63;
    const int quad = ln >> 4, l16 = ln & 15;
    const int pix0 = blockIdx.x * 64;
    const int n0 = blockIdx.y * 128;
    const int b = blockIdx.z;
    const float* xb = x + (size_t)b * Cc * HW;

    f32x4 acc[2][4];
    #pragma unroll
    for (int i = 0; i < 2; i++)
        #pragma unroll
        for (int j = 0; j < 4; j++) acc[i][j] = (f32x4){0.f, 0.f, 0.f, 0.f};

    const int arow = t >> 3, acol = (t & 7) * 8;
    const int bpix = t & 63, bkg = (t >> 6) * 8;
    int pp = pix0 + bpix; if (pp > HW - 1) pp = HW - 1;

    uint4 ra[4];
    float rbx[2][8];

    // prologue: prefetch tile 0
    #pragma unroll
    for (int r = 0; r < 4; r++)
        ra[r] = *(const uint4*)&wbe[(size_t)(n0 + arow + r * 32) * 256 + acol];
    #pragma unroll
    for (int r = 0; r < 2; r++)
        #pragma unroll
        for (int j = 0; j < 8; j++)
            rbx[r][j] = xb[(size_t)(bkg + r * 32 + j) * HW + pp];

    for (int it = 0; it < 4; it++) {
        // commit prefetched tile to LDS
        #pragma unroll
        for (int r = 0; r < 4; r++)
            *(uint4*)&As[(arow + r * 32) * 72 + acol] = ra[r];
        #pragma unroll
        for (int r = 0; r < 2; r++) {
            union { ushort s[8]; uint4 v; } tmp;
            #pragma unroll
            for (int j = 0; j < 8; j++) tmp.s[j] = f2bf(rbx[r][j]);
            *(uint4*)&Bs[bpix * 72 + bkg + r * 32] = tmp.v;
        }
        __syncthreads();
        // prefetch next tile (overlaps with MFMA below)
        if (it < 3) {
            int k0 = (it + 1) * 64;
            #pragma unroll
            for (int r = 0; r < 4; r++)
                ra[r] = *(const uint4*)&wbe[(size_t)(n0 + arow + r * 32) * 256 + k0 + acol];
            #pragma unroll
            for (int r = 0; r < 2; r++)
                #pragma unroll
                for (int j = 0; j < 8; j++)
                    rbx[r][j] = xb[(size_t)(k0 + bkg + r * 32 + j) * HW + pp];
        }
        #pragma unroll
        for (int kk = 0; kk < 64; kk += 32) {
            bfrag af[2], bfr[4];
            #pragma unroll
            for (int dt = 0; dt < 2; dt++)
                af[dt] = *(const bfrag*)&As[(wv * 32 + dt * 16 + l16) * 72 + kk + quad * 8];
            #pragma unroll
            for (int pt = 0; pt < 4; pt++)
                bfr[pt] = *(const bfrag*)&Bs[(pt * 16 + l16) * 72 + kk + quad * 8];
            #pragma unroll
            for (int dt = 0; dt < 2; dt++)
                #pragma unroll
                for (int pt = 0; pt < 4; pt++)
                    acc[dt][pt] = __builtin_amdgcn_mfma_f32_16x16x32_bf16(
                        af[dt], bfr[pt], acc[dt][pt], 0, 0, 0);
        }
        __syncthreads();
    }

    // epilogue: bias, bf16, transpose via LDS (reuse As: [pix][ch] pad 136)
    float bias[2][4];
    #pragma unroll
    for (int dt = 0; dt < 2; dt++)
        #pragma unroll
        for (int r = 0; r < 4; r++)
            bias[dt][r] = efb[n0 + wv * 32 + dt * 16 + quad * 4 + r];
    #pragma unroll
    for (int dt = 0; dt < 2; dt++)
        #pragma unroll
        for (int pt = 0; pt < 4; pt++) {
            int pix = pt * 16 + l16;
            int ch = wv * 32 + dt * 16 + quad * 4;
            ushort4 o = { f2bf(acc[dt][pt][0] + bias[dt][0]),
                          f2bf(acc[dt][pt][1] + bias[dt][1]),
                          f2bf(acc[dt][pt][2] + bias[dt][2]),
                          f2bf(acc[dt][pt][3] + bias[dt][3]) };
            *(ushort4*)&As[pix * 136 + ch] = o;
        }
    __syncthreads();
    const int p = n0 >> 8, cbase = n0 & 255;
    ushort* outb = efp + (size_t)((b * PTS + p) * HW) * Cc;
    #pragma unroll
    for (int r = 0; r < 4; r++) {
        int pix = (t >> 4) + r * 16;
        int ch8 = (t & 15) * 8;
        if (pix0 + pix < HW)
            *(uint4*)&outb[(size_t)(pix0 + pix) * Cc + cbase + ch8] =
                *(const uint4*)&As[pix * 136 + ch8];
    }
}

// ---------------------------------------------------------------------------
// K2: heat[b][p][pix] = exp(sum_d w2[d]*relu(D[d][pix]+b1[d]) + b2)
// Register-prefetch double buffer.
// ---------------------------------------------------------------------------
__global__ __launch_bounds__(256)
void k_heat(const ushort* __restrict__ efp, const ushort* __restrict__ wb1,
            const float* __restrict__ b1, const float* __restrict__ w2,
            const float* __restrict__ b2, float* __restrict__ heat)
{
    __shared__ ushort As[256 * 72];
    __shared__ ushort Bs[64 * 72];
    __shared__ float red[4][64];
    const int t = threadIdx.x;
    const int wv = t >> 6, ln = t & 63;
    const int quad = ln >> 4, l16 = ln & 15;
    const int pix0 = blockIdx.x * 64;
    const int p = blockIdx.y;
    const int b = blockIdx.z;
    const ushort* efb_ = efp + (size_t)((b * PTS + p) * HW) * Cc;
    const ushort* w1p = wb1 + (size_t)p * Cc * Cc;

    f32x4 acc[4][4];
    #pragma unroll
    for (int i = 0; i < 4; i++)
        #pragma unroll
        for (int j = 0; j < 4; j++) acc[i][j] = (f32x4){0.f, 0.f, 0.f, 0.f};

    const int srow = t >> 3, scol = (t & 7) * 8;
    int pbase[2];
    #pragma unroll
    for (int r = 0; r < 2; r++) {
        int pq = pix0 + srow + r * 32; if (pq > HW - 1) pq = HW - 1;
        pbase[r] = pq;
    }

    uint4 ra[8], rb[2];
    #pragma unroll
    for (int r = 0; r < 8; r++)
        ra[r] = *(const uint4*)&w1p[(size_t)(srow + r * 32) * 256 + scol];
    #pragma unroll
    for (int r = 0; r < 2; r++)
        rb[r] = *(const uint4*)&efb_[(size_t)pbase[r] * Cc + scol];

    for (int it = 0; it < 4; it++) {
        #pragma unroll
        for (int r = 0; r < 8; r++)
            *(uint4*)&As[(srow + r * 32) * 72 + scol] = ra[r];
        #pragma unroll
        for (int r = 0; r < 2; r++)
            *(uint4*)&Bs[(srow + r * 32) * 72 + scol] = rb[r];
        __syncthreads();
        if (it < 3) {
            int k0 = (it + 1) * 64;
            #pragma unroll
            for (int r = 0; r < 8; r++)
                ra[r] = *(const uint4*)&w1p[(size_t)(srow + r * 32) * 256 + k0 + scol];
            #pragma unroll
            for (int r = 0; r < 2; r++)
                rb[r] = *(const uint4*)&efb_[(size_t)pbase[r] * Cc + k0 + scol];
        }
        #pragma unroll
        for (int kk = 0; kk < 64; kk += 32) {
            bfrag af[4], bfr[4];
            #pragma unroll
            for (int dt = 0; dt < 4; dt++)
                af[dt] = *(const bfrag*)&As[(wv * 64 + dt * 16 + l16) * 72 + kk + quad * 8];
            #pragma unroll
            for (int pt = 0; pt < 4; pt++)
                bfr[pt] = *(const bfrag*)&Bs[(pt * 16 + l16) * 72 + kk + quad * 8];
            #pragma unroll
            for (int dt = 0; dt < 4; dt++)
                #pragma unroll
                for (int pt = 0; pt < 4; pt++)
                    acc[dt][pt] = __builtin_amdgcn_mfma_f32_16x16x32_bf16(
                        af[dt], bfr[pt], acc[dt][pt], 0, 0, 0);
        }
        __syncthreads();
    }

    const float* b1p = b1 + p * 256;
    const float* w2p = w2 + p * 256;
    float s[4] = {0.f, 0.f, 0.f, 0.f};
    #pragma unroll
    for (int dt = 0; dt < 4; dt++) {
        int chb = wv * 64 + dt * 16 + quad * 4;
        float bb[4], ww[4];
        #pragma unroll
        for (int r = 0; r < 4; r++) { bb[r] = b1p[chb + r]; ww[r] = w2p[chb + r]; }
        #pragma unroll
        for (int pt = 0; pt < 4; pt++)
            #pragma unroll
            for (int r = 0; r < 4; r++) {
                float h = acc[dt][pt][r] + bb[r];
                h = h > 0.f ? h : 0.f;
                s[pt] += ww[r] * h;
            }
    }
    #pragma unroll
    for (int pt = 0; pt < 4; pt++) {
        s[pt] += __shfl_xor(s[pt], 16);
        s[pt] += __shfl_xor(s[pt], 32);
    }
    if (ln < 16) {
        #pragma unroll
        for (int pt = 0; pt < 4; pt++) red[wv][pt * 16 + ln] = s[pt];
    }
    __syncthreads();
    if (t < 64) {
        float v = red[0][t] + red[1][t] + red[2][t] + red[3][t] + b2[p];
        int m = pix0 + t;
        if (m < HW) heat[(size_t)(b * PTS + p) * HW + m] = expf(v);
    }
}

// ---------------------------------------------------------------------------
// K3: deformable sampling. Lane = 4-channel group (uint2 gathers). Wave owns
// 8 pixels, unrolled x2. (weight, byte-offset) packed in LDS. XCD bands.
// ---------------------------------------------------------------------------
__global__ __launch_bounds__(256)
void k_sample(const ushort* __restrict__ efp, const float* __restrict__ heat,
              const float* __restrict__ offs, ushort* __restrict__ outs)
{
    __shared__ uint2 s_wo[32][20];      // {bitcast(weight), byteoff = idx<<9}
    const int t = threadIdx.x;
    const int bid = blockIdx.x;
    const int nx = (bid & 7) * 60 + (bid >> 3);   // XCD-contiguous bands
    if (nx >= 475) return;
    const int m0 = nx * 32;
    const int p = blockIdx.y;
    const int b = blockIdx.z;
    const float* heat_bp = heat + (size_t)(b * PTS + p) * HW;

    if (t < 32 * BINS) {
        int j = t / BINS, k = t % BINS;
        int hw = m0 + j;
        int hh = hw / Ww, ww = hw % Ww;
        int chy = (p * BINS + k) * 2;
        float oy = offs[((size_t)b * (PTS * BINS * 2) + chy)     * HW + hw];
        float ox = offs[((size_t)b * (PTS * BINS * 2) + chy + 1) * HW + hw];
        float ysf = (float)hh + oy;
        float xsf = (float)ww + ox;
        float y0 = floorf(ysf), x0 = floorf(xsf);
        #pragma unroll
        for (int dy = 0; dy < 2; dy++)
            #pragma unroll
            for (int dx = 0; dx < 2; dx++) {
                float yi = y0 + dy, xi = x0 + dx;
                float wgt = (1.f - fabsf(ysf - yi)) * (1.f - fabsf(xsf - xi));
                bool valid = (yi >= 0.f) && (yi <= (float)(Hh - 1)) &&
                             (xi >= 0.f) && (xi <= (float)(Ww - 1));
                int yc = (int)yi; yc = yc < 0 ? 0 : (yc > Hh - 1 ? Hh - 1 : yc);
                int xc = (int)xi; xc = xc < 0 ? 0 : (xc > Ww - 1 ? Ww - 1 : xc);
                int idx = yc * Ww + xc;
                float wh = valid ? wgt * heat_bp[idx] : 0.f;
                s_wo[j][k * 4 + dy * 2 + dx] =
                    make_uint2(__float_as_uint(wh), (unsigned)idx << 9);
            }
    }
    __syncthreads();
    if (t < 32) {
        float s = 0.f;
        #pragma unroll
        for (int u = 0; u < 20; u++) s += __uint_as_float(s_wo[t][u].x);
        float inv = 1.f / (s + EPS_DIV);
        #pragma unroll
        for (int u = 0; u < 20; u++)
            s_wo[t][u].x = __float_as_uint(__uint_as_float(s_wo[t][u].x) * inv);
    }
    __syncthreads();

    // phase 2: lane = 4-channel group; wave wv owns pixels wv*8 .. wv*8+7
    const int wv = t >> 6, ln = t & 63;
    const char* efbase = (const char*)(efp + (size_t)((b * PTS + p) * HW) * Cc)
                         + ln * 8;
    ushort* ob = outs + ((size_t)(b * HW + m0)) * (PTS * Cc) + p * Cc + ln * 4;
    #pragma unroll
    for (int i = 0; i < 8; i += 2) {
        const int j0 = wv * 8 + i, j1 = j0 + 1;
        float a0[4] = {0.f, 0.f, 0.f, 0.f};
        float a1[4] = {0.f, 0.f, 0.f, 0.f};
        #pragma unroll
        for (int u = 0; u < 20; u++) {
            uint2 wo0 = s_wo[j0][u];
            uint2 wo1 = s_wo[j1][u];
            uint2 v0 = *(const uint2*)(efbase + wo0.y);
            uint2 v1 = *(const uint2*)(efbase + wo1.y);
            float w0 = __uint_as_float(wo0.x);
            float w1 = __uint_as_float(wo1.x);
            a0[0] += w0 * bflo(v0.x); a0[1] += w0 * bfhi(v0.x);
            a0[2] += w0 * bflo(v0.y); a0[3] += w0 * bfhi(v0.y);
            a1[0] += w1 * bflo(v1.x); a1[1] += w1 * bfhi(v1.x);
            a1[2] += w1 * bflo(v1.y); a1[3] += w1 * bfhi(v1.y);
        }
        uint2 o0 = make_uint2(pack2(a0[0], a0[1]), pack2(a0[2], a0[3]));
        uint2 o1 = make_uint2(pack2(a1[0], a1[1]), pack2(a1[2], a1[3]));
        *(uint2*)(ob + (size_t)j0 * (PTS * Cc)) = o0;
        *(uint2*)(ob + (size_t)j1 * (PTS * Cc)) = o1;
    }
}

// ---------------------------------------------------------------------------
// K4: out[b][c][pix] (fp32) = merge_w @ outs + merge_b, + fused GN partials.
// Register-prefetch double buffer.
// ---------------------------------------------------------------------------
__global__ __launch_bounds__(256)
void k_merge(const ushort* __restrict__ outs, const ushort* __restrict__ wbm,
             const float* __restrict__ mb, float* __restrict__ out,
             float* __restrict__ part)
{
    __shared__ ushort As[128 * 72];
    __shared__ ushort Bs[64 * 72];
    const int t = threadIdx.x;
    const int wv = t >> 6, ln = t & 63;
    const int quad = ln >> 4, l16 = ln & 15;
    const int pix0 = blockIdx.x * 64;
    const int n0 = blockIdx.y * 128;
    const int b = blockIdx.z;
    const ushort* ob = outs + (size_t)b * HW * (PTS * Cc);

    f32x4 acc[2][4];
    #pragma unroll
    for (int i = 0; i < 2; i++)
        #pragma unroll
        for (int j = 0; j < 4; j++) acc[i][j] = (f32x4){0.f, 0.f, 0.f, 0.f};

    const int srow = t >> 3, scol = (t & 7) * 8;
    int pbase[2];
    #pragma unroll
    for (int r = 0; r < 2; r++) {
        int pq = pix0 + srow + r * 32; if (pq > HW - 1) pq = HW - 1;
        pbase[r] = pq;
    }

    uint4 ra[4], rb[2];
    #pragma unroll
    for (int r = 0; r < 4; r++)
        ra[r] = *(const uint4*)&wbm[(size_t)(n0 + srow + r * 32) * 512 + scol];
    #pragma unroll
    for (int r = 0; r < 2; r++)
        rb[r] = *(const uint4*)&ob[(size_t)pbase[r] * (PTS * Cc) + scol];

    for (int it = 0; it < 8; it++) {
        #pragma unroll
        for (int r = 0; r < 4; r++)
            *(uint4*)&As[(srow + r * 32) * 72 + scol] = ra[r];
        #pragma unroll
        for (int r = 0; r < 2; r++)
            *(uint4*)&Bs[(srow + r * 32) * 72 + scol] = rb[r];
        __syncthreads();
        if (it < 7) {
            int k0 = (it + 1) * 64;
            #pragma unroll
            for (int r = 0; r < 4; r++)
                ra[r] = *(const uint4*)&wbm[(size_t)(n0 + srow + r * 32) * 512 + k0 + scol];
            #pragma unroll
            for (int r = 0; r < 2; r++)
                rb[r] = *(const uint4*)&ob[(size_t)pbase[r] * (PTS * Cc) + k0 + scol];
        }
        #pragma unroll
        for (int kk = 0; kk < 64; kk += 32) {
            bfrag af[2], bfr[4];
            #pragma unroll
            for (int dt = 0; dt < 2; dt++)
                af[dt] = *(const bfrag*)&As[(wv * 32 + dt * 16 + l16) * 72 + kk + quad * 8];
            #pragma unroll
            for (int pt = 0; pt < 4; pt++)
                bfr[pt] = *(const bfrag*)&Bs[(pt * 16 + l16) * 72 + kk + quad * 8];
            #pragma unroll
            for (int dt = 0; dt < 2; dt++)
                #pragma unroll
                for (int pt = 0; pt < 4; pt++)
                    acc[dt][pt] = __builtin_amdgcn_mfma_f32_16x16x32_bf16(
                        af[dt], bfr[pt], acc[dt][pt], 0, 0, 0);
        }
        __syncthreads();
    }

    float bias[2][4];
    #pragma unroll
    for (int dt = 0; dt < 2; dt++)
        #pragma unroll
        for (int r = 0; r < 4; r++)
            bias[dt][r] = mb[n0 + wv * 32 + dt * 16 + quad * 4 + r];

    float sacc[2] = {0.f, 0.f}, qacc[2] = {0.f, 0.f};
    #pragma unroll
    for (int dt = 0; dt < 2; dt++)
        #pragma unroll
        for (int pt = 0; pt < 4; pt++) {
            int ch = n0 + wv * 32 + dt * 16 + quad * 4;
            int pix = pix0 + pt * 16 + l16;
            if (pix < HW) {
                #pragma unroll
                for (int r = 0; r < 4; r++) {
                    float v = acc[dt][pt][r] + bias[dt][r];
                    out[((size_t)b * Cc + ch + r) * HW + pix] = v;
                    sacc[dt] += v; qacc[dt] += v * v;
                }
            }
        }
    // reduce over lanes 0..31 / 32..63 (each half is one 8-ch group per dt)
    #pragma unroll
    for (int dt = 0; dt < 2; dt++) {
        #pragma unroll
        for (int off = 1; off <= 16; off <<= 1) {
            sacc[dt] += __shfl_xor(sacc[dt], off);
            qacc[dt] += __shfl_xor(qacc[dt], off);
        }
        if ((ln & 31) == 0) {
            int g = (n0 >> 3) + wv * 4 + dt * 2 + (ln >> 5);
            atomicAdd(&part[(b * 32 + g) * 2 + 0], sacc[dt]);
            atomicAdd(&part[(b * 32 + g) * 2 + 1], qacc[dt]);
        }
    }
}

// ---------------------------------------------------------------------------
// K5: finalize GN stats (64 groups total)
// ---------------------------------------------------------------------------
__global__ __launch_bounds__(64)
void k_gnfinal(const float* __restrict__ part, float* __restrict__ statf)
{
    int i = threadIdx.x;
    float s = part[i * 2 + 0], q = part[i * 2 + 1];
    const float n = 8.f * HW;
    float mean = s / n;
    float var  = q / n - mean * mean;
    statf[i * 2 + 0] = mean;
    statf[i * 2 + 1] = rsqrtf(var + GN_EPS);
}

// ---------------------------------------------------------------------------
// K6: apply GN scale/shift + ReLU in place
// ---------------------------------------------------------------------------
__global__ __launch_bounds__(256)
void k_gnapply(float* __restrict__ out, const float* __restrict__ statf,
               const float* __restrict__ gg, const float* __restrict__ gb)
{
    const int i4 = blockIdx.x * 256 + threadIdx.x;
    const int total4 = Bx * Cc * HW / 4;
    if (i4 >= total4) return;
    const int i = i4 * 4;
    const int CHW = Cc * HW;
    const int b = i / CHW;
    const int r = i - b * CHW;
    const int c = r / HW;
    const int g = c >> 3;
    float mean = statf[(b * 32 + g) * 2 + 0];
    float istd = statf[(b * 32 + g) * 2 + 1];
    float sc = istd * gg[c];
    float sh = gb[c] - mean * sc;
    float4 v = *(float4*)(out + i);
    v.x = fmaxf(v.x * sc + sh, 0.f);
    v.y = fmaxf(v.y * sc + sh, 0.f);
    v.z = fmaxf(v.z * sc + sh, 0.f);
    v.w = fmaxf(v.w * sc + sh, 0.f);
    *(float4*)(out + i) = v;
}

// ---------------------------------------------------------------------------
extern "C" void kernel_launch(void* const* d_in, const int* in_sizes, int n_in,
                              void* d_out, int out_size, void* d_ws, size_t ws_size,
                              hipStream_t stream)
{
    const float* x    = (const float*)d_in[0];
    const float* offs = (const float*)d_in[1];
    const float* efw  = (const float*)d_in[2];
    const float* efb  = (const float*)d_in[3];
    const float* w1   = (const float*)d_in[4];
    const float* b1   = (const float*)d_in[5];
    const float* w2   = (const float*)d_in[6];
    const float* b2   = (const float*)d_in[7];
    const float* mw   = (const float*)d_in[8];
    const float* mb   = (const float*)d_in[9];
    const float* gg   = (const float*)d_in[10];
    const float* gb   = (const float*)d_in[11];
    float* out = (float*)d_out;

    ushort* wb    = (ushort*)d_ws;
    ushort* wbe   = wb;                          // 131072
    ushort* wb1   = wb + 131072;                 // 131072
    ushort* wbm   = wb + 262144;                 // 131072
    ushort* efp   = wb + 393216;                 // B*P*HW*C bf16
    ushort* outsb = efp + (size_t)Bx * PTS * HW * Cc;
    float*  heat  = (float*)(outsb + (size_t)Bx * HW * PTS * Cc);
    float*  part  = heat + (size_t)Bx * PTS * HW;   // 128 floats
    float*  statf = part + 128;                     // 128 floats

    dim3 blk(256);
    k_wconv  <<<dim3(384),              blk, 0, stream>>>(efw, w1, mw, wb, part);
    k_ef     <<<dim3(238, 4, Bx),       blk, 0, stream>>>(x, wbe, efb, efp);
    k_heat   <<<dim3(238, PTS, Bx),     blk, 0, stream>>>(efp, wb1, b1, w2, b2, heat);
    k_sample <<<dim3(480, PTS, Bx),     blk, 0, stream>>>(efp, heat, offs, outsb);
    k_merge  <<<dim3(238, 2, Bx),       blk, 0, stream>>>(outsb, wbm, mb, out, part);
    k_gnfinal<<<dim3(1), dim3(64),      0, stream>>>(part, statf);
    k_gnapply<<<dim3(Bx * Cc * HW / 4 / 256), blk, 0, stream>>>(out, statf, gg, gb);
}

// Round 6
// 272.984 us; speedup vs baseline: 1.3606x; 1.3606x over previous
//
#include <hip/hip_runtime.h>

#define BINS 5
#define PTS  2
constexpr int Bx = 2, Cc = 256, Hh = 100, Ww = 152;
constexpr int HW = Hh * Ww;          // 15200
constexpr float EPS_DIV = 1e-6f;
constexpr float GN_EPS  = 1e-5f;

typedef __attribute__((ext_vector_type(8))) short bfrag;   // 8 bf16 (4 VGPRs)
typedef __attribute__((ext_vector_type(4))) float f32x4;   // MFMA C/D

__device__ __forceinline__ ushort f2bf(float f) {
    union { float f; unsigned u; } v; v.f = f;
    unsigned r = v.u + 0x7fffu + ((v.u >> 16) & 1u);
    return (ushort)(r >> 16);
}
__device__ __forceinline__ float bf2f(ushort h) {
    union { unsigned u; float f; } v; v.u = ((unsigned)h) << 16;
    return v.f;
}
__device__ __forceinline__ float bflo(unsigned u) {
    return __uint_as_float(u << 16);
}
__device__ __forceinline__ float bfhi(unsigned u) {
    return __uint_as_float(u & 0xffff0000u);
}
__device__ __forceinline__ unsigned pack2(float a, float b) {
    return (unsigned)f2bf(a) | ((unsigned)f2bf(b) << 16);
}

// ---------------------------------------------------------------------------
// K0: convert ef_w, hm1_w, merge_w to bf16 (each 131072 elems) + zero GN parts
// ---------------------------------------------------------------------------
__global__ __launch_bounds__(256)
void k_wconv(const float* __restrict__ efw, const float* __restrict__ w1,
             const float* __restrict__ mw, ushort* __restrict__ wb,
             float* __restrict__ part)
{
    if (blockIdx.x == 0 && threadIdx.x < 128) part[threadIdx.x] = 0.f;
    int gid = blockIdx.x * 256 + threadIdx.x;
    int e = gid * 4;                       // 393216 total elements
    int arr = e >> 17, off = e & 131071;
    const float* src = arr == 0 ? efw : (arr == 1 ? w1 : mw);
    float4 v = *(const float4*)(src + off);
    ushort4 o = { f2bf(v.x), f2bf(v.y), f2bf(v.z), f2bf(v.w) };
    *(ushort4*)(wb + e) = o;
}

// ---------------------------------------------------------------------------
// K1: efp[b][p][pix][c] (bf16) = ef_w @ x + ef_b.  MFMA 16x16x32 bf16.
// (round-4 sync structure; register-prefetch spills — do not reintroduce)
// ---------------------------------------------------------------------------
__global__ __launch_bounds__(256)
void k_ef(const float* __restrict__ x, const ushort* __restrict__ wbe,
          const float* __restrict__ efb, ushort* __restrict__ efp)
{
    __shared__ ushort As[128 * 72];     // [n][k] pad 72
    __shared__ ushort Bs[64 * 72];      // [pix][k]
    const int t = threadIdx.x;
    const int wv = t >> 6, ln = t & 63;
    const int quad = ln >> 4, l16 = ln & 15;
    const int pix0 = blockIdx.x * 64;
    const int n0 = blockIdx.y * 128;
    const int b = blockIdx.z;
    const float* xb = x + (size_t)b * Cc * HW;

    f32x4 acc[2][4];
    #pragma unroll
    for (int i = 0; i < 2; i++)
        #pragma unroll
        for (int j = 0; j < 4; j++) acc[i][j] = (f32x4){0.f, 0.f, 0.f, 0.f};

    const int arow = t >> 3, acol = (t & 7) * 8;
    const int bpix = t & 63, bkg = (t >> 6) * 8;
    int pp = pix0 + bpix; if (pp > HW - 1) pp = HW - 1;

    for (int k0 = 0; k0 < 256; k0 += 64) {
        #pragma unroll
        for (int r = 0; r < 4; r++) {
            int row = arow + r * 32;
            *(uint4*)&As[row * 72 + acol] =
                *(const uint4*)&wbe[(size_t)(n0 + row) * 256 + k0 + acol];
        }
        #pragma unroll
        for (int r = 0; r < 2; r++) {
            int kc = bkg + r * 32;
            union { ushort s[8]; uint4 v; } tmp;
            #pragma unroll
            for (int j = 0; j < 8; j++)
                tmp.s[j] = f2bf(xb[(size_t)(k0 + kc + j) * HW + pp]);
            *(uint4*)&Bs[bpix * 72 + kc] = tmp.v;
        }
        __syncthreads();
        #pragma unroll
        for (int kk = 0; kk < 64; kk += 32) {
            bfrag af[2], bfr[4];
            #pragma unroll
            for (int dt = 0; dt < 2; dt++)
                af[dt] = *(const bfrag*)&As[(wv * 32 + dt * 16 + l16) * 72 + kk + quad * 8];
            #pragma unroll
            for (int pt = 0; pt < 4; pt++)
                bfr[pt] = *(const bfrag*)&Bs[(pt * 16 + l16) * 72 + kk + quad * 8];
            #pragma unroll
            for (int dt = 0; dt < 2; dt++)
                #pragma unroll
                for (int pt = 0; pt < 4; pt++)
                    acc[dt][pt] = __builtin_amdgcn_mfma_f32_16x16x32_bf16(
                        af[dt], bfr[pt], acc[dt][pt], 0, 0, 0);
        }
        __syncthreads();
    }

    // epilogue: bias, bf16, transpose via LDS (reuse As: [pix][ch] pad 136)
    float bias[2][4];
    #pragma unroll
    for (int dt = 0; dt < 2; dt++)
        #pragma unroll
        for (int r = 0; r < 4; r++)
            bias[dt][r] = efb[n0 + wv * 32 + dt * 16 + quad * 4 + r];
    #pragma unroll
    for (int dt = 0; dt < 2; dt++)
        #pragma unroll
        for (int pt = 0; pt < 4; pt++) {
            int pix = pt * 16 + l16;
            int ch = wv * 32 + dt * 16 + quad * 4;
            ushort4 o = { f2bf(acc[dt][pt][0] + bias[dt][0]),
                          f2bf(acc[dt][pt][1] + bias[dt][1]),
                          f2bf(acc[dt][pt][2] + bias[dt][2]),
                          f2bf(acc[dt][pt][3] + bias[dt][3]) };
            *(ushort4*)&As[pix * 136 + ch] = o;
        }
    __syncthreads();
    const int p = n0 >> 8, cbase = n0 & 255;
    ushort* outb = efp + (size_t)((b * PTS + p) * HW) * Cc;
    #pragma unroll
    for (int r = 0; r < 4; r++) {
        int pix = (t >> 4) + r * 16;
        int ch8 = (t & 15) * 8;
        if (pix0 + pix < HW)
            *(uint4*)&outb[(size_t)(pix0 + pix) * Cc + cbase + ch8] =
                *(const uint4*)&As[pix * 136 + ch8];
    }
}

// ---------------------------------------------------------------------------
// K2: heat[b][p][pix] = exp(sum_d w2[d]*relu(D[d][pix]+b1[d]) + b2)
// (round-4 sync structure)
// ---------------------------------------------------------------------------
__global__ __launch_bounds__(256)
void k_heat(const ushort* __restrict__ efp, const ushort* __restrict__ wb1,
            const float* __restrict__ b1, const float* __restrict__ w2,
            const float* __restrict__ b2, float* __restrict__ heat)
{
    __shared__ ushort As[256 * 72];
    __shared__ ushort Bs[64 * 72];
    __shared__ float red[4][64];
    const int t = threadIdx.x;
    const int wv = t >> 6, ln = t & 63;
    const int quad = ln >> 4, l16 = ln & 15;
    const int pix0 = blockIdx.x * 64;
    const int p = blockIdx.y;
    const int b = blockIdx.z;
    const ushort* efb_ = efp + (size_t)((b * PTS + p) * HW) * Cc;
    const ushort* w1p = wb1 + (size_t)p * Cc * Cc;

    f32x4 acc[4][4];
    #pragma unroll
    for (int i = 0; i < 4; i++)
        #pragma unroll
        for (int j = 0; j < 4; j++) acc[i][j] = (f32x4){0.f, 0.f, 0.f, 0.f};

    const int srow = t >> 3, scol = (t & 7) * 8;

    for (int k0 = 0; k0 < 256; k0 += 64) {
        #pragma unroll
        for (int r = 0; r < 8; r++) {
            int row = srow + r * 32;
            *(uint4*)&As[row * 72 + scol] =
                *(const uint4*)&w1p[(size_t)row * 256 + k0 + scol];
        }
        #pragma unroll
        for (int r = 0; r < 2; r++) {
            int row = srow + r * 32;
            int pq = pix0 + row; if (pq > HW - 1) pq = HW - 1;
            *(uint4*)&Bs[row * 72 + scol] =
                *(const uint4*)&efb_[(size_t)pq * Cc + k0 + scol];
        }
        __syncthreads();
        #pragma unroll
        for (int kk = 0; kk < 64; kk += 32) {
            bfrag af[4], bfr[4];
            #pragma unroll
            for (int dt = 0; dt < 4; dt++)
                af[dt] = *(const bfrag*)&As[(wv * 64 + dt * 16 + l16) * 72 + kk + quad * 8];
            #pragma unroll
            for (int pt = 0; pt < 4; pt++)
                bfr[pt] = *(const bfrag*)&Bs[(pt * 16 + l16) * 72 + kk + quad * 8];
            #pragma unroll
            for (int dt = 0; dt < 4; dt++)
                #pragma unroll
                for (int pt = 0; pt < 4; pt++)
                    acc[dt][pt] = __builtin_amdgcn_mfma_f32_16x16x32_bf16(
                        af[dt], bfr[pt], acc[dt][pt], 0, 0, 0);
        }
        __syncthreads();
    }

    const float* b1p = b1 + p * 256;
    const float* w2p = w2 + p * 256;
    float s[4] = {0.f, 0.f, 0.f, 0.f};
    #pragma unroll
    for (int dt = 0; dt < 4; dt++) {
        int chb = wv * 64 + dt * 16 + quad * 4;
        float bb[4], ww[4];
        #pragma unroll
        for (int r = 0; r < 4; r++) { bb[r] = b1p[chb + r]; ww[r] = w2p[chb + r]; }
        #pragma unroll
        for (int pt = 0; pt < 4; pt++)
            #pragma unroll
            for (int r = 0; r < 4; r++) {
                float h = acc[dt][pt][r] + bb[r];
                h = h > 0.f ? h : 0.f;
                s[pt] += ww[r] * h;
            }
    }
    #pragma unroll
    for (int pt = 0; pt < 4; pt++) {
        s[pt] += __shfl_xor(s[pt], 16);
        s[pt] += __shfl_xor(s[pt], 32);
    }
    if (ln < 16) {
        #pragma unroll
        for (int pt = 0; pt < 4; pt++) red[wv][pt * 16 + ln] = s[pt];
    }
    __syncthreads();
    if (t < 64) {
        float v = red[0][t] + red[1][t] + red[2][t] + red[3][t] + b2[p];
        int m = pix0 + t;
        if (m < HW) heat[(size_t)(b * PTS + p) * HW + m] = expf(v);
    }
}

// ---------------------------------------------------------------------------
// K3: deformable sampling. Lane = 4-channel group (uint2 gathers). Wave owns
// 8 pixels, unrolled x2. (weight, byte-offset) packed in LDS. XCD bands.
// ---------------------------------------------------------------------------
__global__ __launch_bounds__(256)
void k_sample(const ushort* __restrict__ efp, const float* __restrict__ heat,
              const float* __restrict__ offs, ushort* __restrict__ outs)
{
    __shared__ uint2 s_wo[32][20];      // {bitcast(weight), byteoff = idx<<9}
    const int t = threadIdx.x;
    const int bid = blockIdx.x;
    const int nx = (bid & 7) * 60 + (bid >> 3);   // XCD-contiguous bands
    if (nx >= 475) return;
    const int m0 = nx * 32;
    const int p = blockIdx.y;
    const int b = blockIdx.z;
    const float* heat_bp = heat + (size_t)(b * PTS + p) * HW;

    if (t < 32 * BINS) {
        int j = t / BINS, k = t % BINS;
        int hw = m0 + j;
        int hh = hw / Ww, ww = hw % Ww;
        int chy = (p * BINS + k) * 2;
        float oy = offs[((size_t)b * (PTS * BINS * 2) + chy)     * HW + hw];
        float ox = offs[((size_t)b * (PTS * BINS * 2) + chy + 1) * HW + hw];
        float ysf = (float)hh + oy;
        float xsf = (float)ww + ox;
        float y0 = floorf(ysf), x0 = floorf(xsf);
        #pragma unroll
        for (int dy = 0; dy < 2; dy++)
            #pragma unroll
            for (int dx = 0; dx < 2; dx++) {
                float yi = y0 + dy, xi = x0 + dx;
                float wgt = (1.f - fabsf(ysf - yi)) * (1.f - fabsf(xsf - xi));
                bool valid = (yi >= 0.f) && (yi <= (float)(Hh - 1)) &&
                             (xi >= 0.f) && (xi <= (float)(Ww - 1));
                int yc = (int)yi; yc = yc < 0 ? 0 : (yc > Hh - 1 ? Hh - 1 : yc);
                int xc = (int)xi; xc = xc < 0 ? 0 : (xc > Ww - 1 ? Ww - 1 : xc);
                int idx = yc * Ww + xc;
                float wh = valid ? wgt * heat_bp[idx] : 0.f;
                s_wo[j][k * 4 + dy * 2 + dx] =
                    make_uint2(__float_as_uint(wh), (unsigned)idx << 9);
            }
    }
    __syncthreads();
    if (t < 32) {
        float s = 0.f;
        #pragma unroll
        for (int u = 0; u < 20; u++) s += __uint_as_float(s_wo[t][u].x);
        float inv = 1.f / (s + EPS_DIV);
        #pragma unroll
        for (int u = 0; u < 20; u++)
            s_wo[t][u].x = __float_as_uint(__uint_as_float(s_wo[t][u].x) * inv);
    }
    __syncthreads();

    // phase 2: lane = 4-channel group; wave wv owns pixels wv*8 .. wv*8+7
    const int wv = t >> 6, ln = t & 63;
    const char* efbase = (const char*)(efp + (size_t)((b * PTS + p) * HW) * Cc)
                         + ln * 8;
    ushort* ob = outs + ((size_t)(b * HW + m0)) * (PTS * Cc) + p * Cc + ln * 4;
    #pragma unroll
    for (int i = 0; i < 8; i += 2) {
        const int j0 = wv * 8 + i, j1 = j0 + 1;
        float a0[4] = {0.f, 0.f, 0.f, 0.f};
        float a1[4] = {0.f, 0.f, 0.f, 0.f};
        #pragma unroll
        for (int u = 0; u < 20; u++) {
            uint2 wo0 = s_wo[j0][u];
            uint2 wo1 = s_wo[j1][u];
            uint2 v0 = *(const uint2*)(efbase + wo0.y);
            uint2 v1 = *(const uint2*)(efbase + wo1.y);
            float w0 = __uint_as_float(wo0.x);
            float w1 = __uint_as_float(wo1.x);
            a0[0] += w0 * bflo(v0.x); a0[1] += w0 * bfhi(v0.x);
            a0[2] += w0 * bflo(v0.y); a0[3] += w0 * bfhi(v0.y);
            a1[0] += w1 * bflo(v1.x); a1[1] += w1 * bfhi(v1.x);
            a1[2] += w1 * bflo(v1.y); a1[3] += w1 * bfhi(v1.y);
        }
        uint2 o0 = make_uint2(pack2(a0[0], a0[1]), pack2(a0[2], a0[3]));
        uint2 o1 = make_uint2(pack2(a1[0], a1[1]), pack2(a1[2], a1[3]));
        *(uint2*)(ob + (size_t)j0 * (PTS * Cc)) = o0;
        *(uint2*)(ob + (size_t)j1 * (PTS * Cc)) = o1;
    }
}

// ---------------------------------------------------------------------------
// K4: out[b][c][pix] (fp32) = merge_w @ outs + merge_b, + fused GN partials.
// BN=64 tile: LDS 18.4 KB -> 8 blocks/CU, 1904 blocks (latency hiding via
// occupancy; register prefetch spilled — see round-5 post-mortem).
// ---------------------------------------------------------------------------
__global__ __launch_bounds__(256)
void k_merge(const ushort* __restrict__ outs, const ushort* __restrict__ wbm,
             const float* __restrict__ mb, float* __restrict__ out,
             float* __restrict__ part)
{
    __shared__ ushort As[64 * 72];      // [n][k]
    __shared__ ushort Bs[64 * 72];      // [pix][k]
    const int t = threadIdx.x;
    const int wv = t >> 6, ln = t & 63;
    const int quad = ln >> 4, l16 = ln & 15;
    const int pix0 = blockIdx.x * 64;
    const int n0 = blockIdx.y * 64;
    const int b = blockIdx.z;
    const ushort* ob = outs + (size_t)b * HW * (PTS * Cc);

    f32x4 acc[4];
    #pragma unroll
    for (int j = 0; j < 4; j++) acc[j] = (f32x4){0.f, 0.f, 0.f, 0.f};

    const int srow = t >> 3, scol = (t & 7) * 8;   // srow 0..31

    for (int k0 = 0; k0 < 512; k0 += 64) {
        #pragma unroll
        for (int r = 0; r < 2; r++) {
            int row = srow + r * 32;
            *(uint4*)&As[row * 72 + scol] =
                *(const uint4*)&wbm[(size_t)(n0 + row) * 512 + k0 + scol];
        }
        #pragma unroll
        for (int r = 0; r < 2; r++) {
            int row = srow + r * 32;
            int pq = pix0 + row; if (pq > HW - 1) pq = HW - 1;
            *(uint4*)&Bs[row * 72 + scol] =
                *(const uint4*)&ob[(size_t)pq * (PTS * Cc) + k0 + scol];
        }
        __syncthreads();
        #pragma unroll
        for (int kk = 0; kk < 64; kk += 32) {
            bfrag af = *(const bfrag*)&As[(wv * 16 + l16) * 72 + kk + quad * 8];
            #pragma unroll
            for (int pt = 0; pt < 4; pt++) {
                bfrag bfr = *(const bfrag*)&Bs[(pt * 16 + l16) * 72 + kk + quad * 8];
                acc[pt] = __builtin_amdgcn_mfma_f32_16x16x32_bf16(
                    af, bfr, acc[pt], 0, 0, 0);
            }
        }
        __syncthreads();
    }

    const int ch = n0 + wv * 16 + quad * 4;
    float bias[4];
    #pragma unroll
    for (int r = 0; r < 4; r++) bias[r] = mb[ch + r];

    float sacc = 0.f, qacc = 0.f;
    #pragma unroll
    for (int pt = 0; pt < 4; pt++) {
        int pix = pix0 + pt * 16 + l16;
        if (pix < HW) {
            #pragma unroll
            for (int r = 0; r < 4; r++) {
                float v = acc[pt][r] + bias[r];
                out[((size_t)b * Cc + ch + r) * HW + pix] = v;
                sacc += v; qacc += v * v;
            }
        }
    }
    // lanes 0..31 cover group (n0>>3)+wv*2, lanes 32..63 the next group
    #pragma unroll
    for (int off = 1; off <= 16; off <<= 1) {
        sacc += __shfl_xor(sacc, off);
        qacc += __shfl_xor(qacc, off);
    }
    if ((ln & 31) == 0) {
        int g = (n0 >> 3) + wv * 2 + (quad >> 1);
        atomicAdd(&part[(b * 32 + g) * 2 + 0], sacc);
        atomicAdd(&part[(b * 32 + g) * 2 + 1], qacc);
    }
}

// ---------------------------------------------------------------------------
// K5: finalize GN stats (64 groups total)
// ---------------------------------------------------------------------------
__global__ __launch_bounds__(64)
void k_gnfinal(const float* __restrict__ part, float* __restrict__ statf)
{
    int i = threadIdx.x;
    float s = part[i * 2 + 0], q = part[i * 2 + 1];
    const float n = 8.f * HW;
    float mean = s / n;
    float var  = q / n - mean * mean;
    statf[i * 2 + 0] = mean;
    statf[i * 2 + 1] = rsqrtf(var + GN_EPS);
}

// ---------------------------------------------------------------------------
// K6: apply GN scale/shift + ReLU in place
// ---------------------------------------------------------------------------
__global__ __launch_bounds__(256)
void k_gnapply(float* __restrict__ out, const float* __restrict__ statf,
               const float* __restrict__ gg, const float* __restrict__ gb)
{
    const int i4 = blockIdx.x * 256 + threadIdx.x;
    const int total4 = Bx * Cc * HW / 4;
    if (i4 >= total4) return;
    const int i = i4 * 4;
    const int CHW = Cc * HW;
    const int b = i / CHW;
    const int r = i - b * CHW;
    const int c = r / HW;
    const int g = c >> 3;
    float mean = statf[(b * 32 + g) * 2 + 0];
    float istd = statf[(b * 32 + g) * 2 + 1];
    float sc = istd * gg[c];
    float sh = gb[c] - mean * sc;
    float4 v = *(float4*)(out + i);
    v.x = fmaxf(v.x * sc + sh, 0.f);
    v.y = fmaxf(v.y * sc + sh, 0.f);
    v.z = fmaxf(v.z * sc + sh, 0.f);
    v.w = fmaxf(v.w * sc + sh, 0.f);
    *(float4*)(out + i) = v;
}

// ---------------------------------------------------------------------------
extern "C" void kernel_launch(void* const* d_in, const int* in_sizes, int n_in,
                              void* d_out, int out_size, void* d_ws, size_t ws_size,
                              hipStream_t stream)
{
    const float* x    = (const float*)d_in[0];
    const float* offs = (const float*)d_in[1];
    const float* efw  = (const float*)d_in[2];
    const float* efb  = (const float*)d_in[3];
    const float* w1   = (const float*)d_in[4];
    const float* b1   = (const float*)d_in[5];
    const float* w2   = (const float*)d_in[6];
    const float* b2   = (const float*)d_in[7];
    const float* mw   = (const float*)d_in[8];
    const float* mb   = (const float*)d_in[9];
    const float* gg   = (const float*)d_in[10];
    const float* gb   = (const float*)d_in[11];
    float* out = (float*)d_out;

    ushort* wb    = (ushort*)d_ws;
    ushort* wbe   = wb;                          // 131072
    ushort* wb1   = wb + 131072;                 // 131072
    ushort* wbm   = wb + 262144;                 // 131072
    ushort* efp   = wb + 393216;                 // B*P*HW*C bf16
    ushort* outsb = efp + (size_t)Bx * PTS * HW * Cc;
    float*  heat  = (float*)(outsb + (size_t)Bx * HW * PTS * Cc);
    float*  part  = heat + (size_t)Bx * PTS * HW;   // 128 floats
    float*  statf = part + 128;                     // 128 floats

    dim3 blk(256);
    k_wconv  <<<dim3(384),              blk, 0, stream>>>(efw, w1, mw, wb, part);
    k_ef     <<<dim3(238, 4, Bx),       blk, 0, stream>>>(x, wbe, efb, efp);
    k_heat   <<<dim3(238, PTS, Bx),     blk, 0, stream>>>(efp, wb1, b1, w2, b2, heat);
    k_sample <<<dim3(480, PTS, Bx),     blk, 0, stream>>>(efp, heat, offs, outsb);
    k_merge  <<<dim3(238, 4, Bx),       blk, 0, stream>>>(outsb, wbm, mb, out, part);
    k_gnfinal<<<dim3(1), dim3(64),      0, stream>>>(part, statf);
    k_gnapply<<<dim3(Bx * Cc * HW / 4 / 256), blk, 0, stream>>>(out, statf, gg, gb);
}